// Round 1
// baseline (3048.957 us; speedup 1.0000x reference)
//
#include <hip/hip_runtime.h>

__device__ __forceinline__ float silu_f(float v) {
    // v * sigmoid(v); rcp+exp are ~1ulp hardware ops, far within 2% threshold
    return v * __builtin_amdgcn_rcpf(1.0f + __expf(-v));
}

// Generic 3x3 conv, pad=1, stride S, fused SiLU, optional fused residual add.
// Output n-stride is Cout*Hout*Wout (compact); input may live inside a larger
// tensor (channel-split views) via inNStride / base-pointer offset.
template <int CIN, int S, bool RESID>
__global__ __launch_bounds__(256) void conv3x3_k(
    const float* __restrict__ in, long inNStride,
    const float* __restrict__ w, const float* __restrict__ bias,
    float* __restrict__ out,
    const float* __restrict__ resid, long residNStride,
    int Hin, int Win, int Hout, int Wout)
{
    const int tid = threadIdx.x;
    const int tilesx = Wout >> 4;                // Wout divisible by 16
    const int bx = blockIdx.x % tilesx;
    const int by = blockIdx.x / tilesx;
    const int co = blockIdx.y;
    const int n  = blockIdx.z;
    const int Cout = gridDim.y;

    const int ox = (bx << 4) + (tid & 15);
    const int oy = (by << 4) + (tid >> 4);

    const float* wp = w + co * CIN * 9;
    const float* ip = in + (long)n * inNStride;

    float acc = bias[co];

    const int ix0 = (bx << 4) * S - 1;
    const int iy0 = (by << 4) * S - 1;
    const bool interior = (ix0 >= 0) && (ix0 + 15 * S + 2 < Win) &&
                          (iy0 >= 0) && (iy0 + 15 * S + 2 < Hin);

    if (interior) {
        const float* prow = ip + (long)(oy * S - 1) * Win + (ox * S - 1);
        #pragma unroll 4
        for (int ci = 0; ci < CIN; ++ci) {
            #pragma unroll
            for (int ky = 0; ky < 3; ++ky) {
                const float* r = prow + ((long)ci * Hin + ky) * Win;
                const float* wk = wp + ci * 9 + ky * 3;
                acc += r[0] * wk[0];
                acc += r[1] * wk[1];
                acc += r[2] * wk[2];
            }
        }
    } else {
        #pragma unroll 4
        for (int ci = 0; ci < CIN; ++ci) {
            #pragma unroll
            for (int ky = 0; ky < 3; ++ky) {
                const int iy = oy * S - 1 + ky;
                if (iy < 0 || iy >= Hin) continue;
                const float* r = ip + ((long)ci * Hin + iy) * Win;
                const float* wk = wp + ci * 9 + ky * 3;
                #pragma unroll
                for (int kx = 0; kx < 3; ++kx) {
                    const int ix = ox * S - 1 + kx;
                    const float v = (ix >= 0 && ix < Win) ? r[ix] : 0.0f;
                    acc += v * wk[kx];
                }
            }
        }
    }

    float v = silu_f(acc);
    if (RESID) {
        v += resid[(long)n * residNStride + (long)co * Hout * Wout + oy * Wout + ox];
    }
    out[(((long)n * Cout + co) * Hout + oy) * Wout + ox] = v;
}

// 1x1 conv 64->64 over 25600 pixels, 8 output channels per thread, fused SiLU.
__global__ __launch_bounds__(256) void conv1x1_64_k(
    const float* __restrict__ in, const float* __restrict__ w,
    const float* __restrict__ bias, float* __restrict__ out)
{
    const int tid = threadIdx.x;
    const int p   = blockIdx.x * 256 + tid;    // 0..25599
    const int co0 = blockIdx.y * 8;
    const int n   = blockIdx.z;

    float acc[8];
    #pragma unroll
    for (int j = 0; j < 8; ++j) acc[j] = bias[co0 + j];

    const float* ip = in + (long)n * 64 * 25600 + p;
    #pragma unroll 8
    for (int ci = 0; ci < 64; ++ci) {
        const float v = ip[ci * 25600];
        #pragma unroll
        for (int j = 0; j < 8; ++j) acc[j] += v * w[(co0 + j) * 64 + ci];
    }

    float* op = out + (long)n * 64 * 25600 + p;
    #pragma unroll
    for (int j = 0; j < 8; ++j) op[(co0 + j) * 25600] = silu_f(acc[j]);
}

// 1x1 conv over implicit concat [y(64ch) ; b(32ch)] -> 64 ch, fused SiLU.
__global__ __launch_bounds__(256) void conv1x1_cat_k(
    const float* __restrict__ y, const float* __restrict__ bb,
    const float* __restrict__ w, const float* __restrict__ bias,
    float* __restrict__ out)
{
    const int tid = threadIdx.x;
    const int p   = blockIdx.x * 256 + tid;
    const int co0 = blockIdx.y * 8;
    const int n   = blockIdx.z;

    float acc[8];
    #pragma unroll
    for (int j = 0; j < 8; ++j) acc[j] = bias[co0 + j];

    const float* yp = y + (long)n * 64 * 25600 + p;
    #pragma unroll 8
    for (int ci = 0; ci < 64; ++ci) {
        const float v = yp[ci * 25600];
        #pragma unroll
        for (int j = 0; j < 8; ++j) acc[j] += v * w[(co0 + j) * 96 + ci];
    }
    const float* bp = bb + (long)n * 32 * 25600 + p;
    #pragma unroll 8
    for (int ci = 0; ci < 32; ++ci) {
        const float v = bp[ci * 25600];
        #pragma unroll
        for (int j = 0; j < 8; ++j) acc[j] += v * w[(co0 + j) * 96 + 64 + ci];
    }

    float* op = out + (long)n * 64 * 25600 + p;
    #pragma unroll
    for (int j = 0; j < 8; ++j) op[(co0 + j) * 25600] = silu_f(acc[j]);
}

extern "C" void kernel_launch(void* const* d_in, const int* in_sizes, int n_in,
                              void* d_out, int out_size, void* d_ws, size_t ws_size,
                              hipStream_t stream) {
    const float* x   = (const float*)d_in[0];
    const float* w0  = (const float*)d_in[1];
    const float* b0  = (const float*)d_in[2];
    const float* w1  = (const float*)d_in[3];
    const float* b1  = (const float*)d_in[4];
    const float* wc0 = (const float*)d_in[5];
    const float* bc0 = (const float*)d_in[6];
    const float* wb1 = (const float*)d_in[7];
    const float* bb1 = (const float*)d_in[8];
    const float* wb2 = (const float*)d_in[9];
    const float* bb2 = (const float*)d_in[10];
    const float* wc1 = (const float*)d_in[11];
    const float* bc1 = (const float*)d_in[12];
    const float* w3  = (const float*)d_in[13];
    const float* b3  = (const float*)d_in[14];
    float* out = (float*)d_out;
    float* ws  = (float*)d_ws;

    // Workspace layout (floats), peak 39,321,600 floats = 157.3 MB:
    //   h0  [8,32,320,320] @ 0          (26,214,400)
    //   h1  [8,64,160,160] @ 26,214,400 (13,107,200)
    //   y   [8,64,160,160] @ 0            (reuses dead h0)
    //   b1f [8,32,160,160] @ 13,107,200   (reuses dead h0)
    //   bf  [8,32,160,160] @ 19,660,800   (reuses dead h0)
    //   h2  [8,64,160,160] @ 26,214,400   (reuses dead h1)
    float* h0  = ws;
    float* h1  = ws + 26214400L;
    float* yb  = ws;
    float* b1f = ws + 13107200L;
    float* bf  = ws + 19660800L;
    float* h2  = ws + 26214400L;

    const dim3 blk(256, 1, 1);

    // conv0: 3->32, s2, 640->320
    conv3x3_k<3, 2, false><<<dim3(400, 32, 8), blk, 0, stream>>>(
        x, 3L * 640 * 640, w0, b0, h0, nullptr, 0, 640, 640, 320, 320);

    // conv1: 32->64, s2, 320->160
    conv3x3_k<32, 2, false><<<dim3(100, 64, 8), blk, 0, stream>>>(
        h0, 32L * 320 * 320, w1, b1, h1, nullptr, 0, 320, 320, 160, 160);

    // wc0: 1x1 64->64 on h1 -> y
    conv1x1_64_k<<<dim3(100, 8, 8), blk, 0, stream>>>(h1, wc0, bc0, yb);

    // wb1: 3x3 s1 32->32 on x2 (= y channels 32..63) -> b1f
    conv3x3_k<32, 1, false><<<dim3(100, 32, 8), blk, 0, stream>>>(
        yb + 32 * 25600, 64L * 25600, wb1, bb1, b1f, nullptr, 0, 160, 160, 160, 160);

    // wb2: 3x3 s1 32->32 on b1f, + residual x2 -> bf
    conv3x3_k<32, 1, true><<<dim3(100, 32, 8), blk, 0, stream>>>(
        b1f, 32L * 25600, wb2, bb2, bf, yb + 32 * 25600, 64L * 25600,
        160, 160, 160, 160);

    // wc1: 1x1 on concat([y(64), bf(32)]) -> 64 -> h2
    conv1x1_cat_k<<<dim3(100, 8, 8), blk, 0, stream>>>(yb, bf, wc1, bc1, h2);

    // conv3: 3x3 s2 64->128, 160->80 -> out
    conv3x3_k<64, 2, false><<<dim3(25, 128, 8), blk, 0, stream>>>(
        h2, 64L * 25600, w3, b3, out, nullptr, 0, 160, 160, 80, 80);
}

// Round 2
// 901.292 us; speedup vs baseline: 3.3829x; 3.3829x over previous
//
#include <hip/hip_runtime.h>

__device__ __forceinline__ float silu_f(float v) {
    return v * __builtin_amdgcn_rcpf(1.0f + __expf(-v));
}

// 3x3 conv, pad=1, stride S. Each block: 16x16 output tile x CO output
// channels (register-blocked). Per input channel: stage zero-padded input
// tile in LDS, 9 taps -> registers, CO*9 FMAs with scalar weights.
// Weights OIHW [CoutTotal][CIN][3][3]. Fused SiLU + optional residual.
template <int CIN, int CO, int S, bool RESID>
__global__ __launch_bounds__(256) void conv3x3_lds(
    const float* __restrict__ in, long inNStride,
    const float* __restrict__ w, const float* __restrict__ bias,
    float* __restrict__ out, long outNStride,
    const float* __restrict__ resid, long residNStride,
    int Hin, int Win, int Hout, int Wout)
{
    constexpr int IT = 15 * S + 3;          // S=1: 18, S=2: 33
    __shared__ float tile[IT * IT];

    const int tid = threadIdx.x;
    const int tilesx = Wout >> 4;
    const int bx = blockIdx.x % tilesx;
    const int by = blockIdx.x / tilesx;
    const int co0 = blockIdx.y * CO;
    const int n  = blockIdx.z;

    const int tx = tid & 15, ty = tid >> 4;
    const int ox = (bx << 4) + tx, oy = (by << 4) + ty;

    const int ix0 = (bx << 4) * S - 1;
    const int iy0 = (by << 4) * S - 1;

    float acc[CO];
    #pragma unroll
    for (int j = 0; j < CO; ++j) acc[j] = bias[co0 + j];

    const float* ip = in + (long)n * inNStride;

    for (int ci = 0; ci < CIN; ++ci) {
        const float* plane = ip + (long)ci * Hin * Win;
        __syncthreads();                    // previous iter's LDS reads done
        for (int t = tid; t < IT * IT; t += 256) {
            const int ly = t / IT, lx = t - ly * IT;
            const int iy = iy0 + ly, ix = ix0 + lx;
            float v = 0.0f;
            if (iy >= 0 && iy < Hin && ix >= 0 && ix < Win)
                v = plane[(long)iy * Win + ix];
            tile[t] = v;
        }
        __syncthreads();

        float v[9];
        #pragma unroll
        for (int ky = 0; ky < 3; ++ky)
            #pragma unroll
            for (int kx = 0; kx < 3; ++kx)
                v[ky * 3 + kx] = tile[(ty * S + ky) * IT + tx * S + kx];

        const float* wp = w + ((long)co0 * CIN + ci) * 9;
        #pragma unroll
        for (int j = 0; j < CO; ++j) {
            const float* w9 = wp + (long)j * CIN * 9;   // uniform -> s_load
            #pragma unroll
            for (int k = 0; k < 9; ++k) acc[j] += v[k] * w9[k];
        }
    }

    const long HW = (long)Hout * Wout;
    float* op = out + (long)n * outNStride + (long)co0 * HW + (long)oy * Wout + ox;
    const float* rp = nullptr;
    if (RESID)
        rp = resid + (long)n * residNStride + (long)oy * Wout + ox;
    #pragma unroll
    for (int j = 0; j < CO; ++j) {
        float r = silu_f(acc[j]);
        if (RESID) r += rp[(long)(co0 + j) * HW];
        op[(long)j * HW] = r;
    }
}

// 1x1 conv over (optionally concatenated) NCHW input. Thread = one pixel,
// CO output channels in registers; input read in 32-channel register chunks.
// Weights [CoutTotal][CIN1+CIN2].
template <int CIN1, int CIN2, int CO>
__global__ __launch_bounds__(256) void conv1x1_k(
    const float* __restrict__ in1, long n1s,
    const float* __restrict__ in2, long n2s,
    const float* __restrict__ w, const float* __restrict__ bias,
    float* __restrict__ out, long onS, int HW)
{
    constexpr int CIN = CIN1 + CIN2;
    const int p   = blockIdx.x * 256 + threadIdx.x;
    const int co0 = blockIdx.y * CO;
    const int n   = blockIdx.z;

    float acc[CO];
    #pragma unroll
    for (int j = 0; j < CO; ++j) acc[j] = bias[co0 + j];

    const float* p1 = in1 + (long)n * n1s + p;
    const float* p2 = in2 + (long)n * n2s + p;

    #pragma unroll
    for (int cc = 0; cc < CIN; cc += 32) {
        float v[32];
        #pragma unroll
        for (int k = 0; k < 32; ++k) {
            const int ci = cc + k;
            v[k] = (ci < CIN1) ? p1[(long)ci * HW]
                               : p2[(long)(ci - CIN1) * HW];
        }
        #pragma unroll
        for (int j = 0; j < CO; ++j) {
            const float* wr = w + (long)(co0 + j) * CIN + cc;  // uniform
            #pragma unroll
            for (int k = 0; k < 32; ++k) acc[j] += v[k] * wr[k];
        }
    }

    float* op = out + (long)n * onS + (long)co0 * HW + p;
    #pragma unroll
    for (int j = 0; j < CO; ++j) op[(long)j * HW] = silu_f(acc[j]);
}

extern "C" void kernel_launch(void* const* d_in, const int* in_sizes, int n_in,
                              void* d_out, int out_size, void* d_ws, size_t ws_size,
                              hipStream_t stream) {
    const float* x   = (const float*)d_in[0];
    const float* w0  = (const float*)d_in[1];
    const float* b0  = (const float*)d_in[2];
    const float* w1  = (const float*)d_in[3];
    const float* b1  = (const float*)d_in[4];
    const float* wc0 = (const float*)d_in[5];
    const float* bc0 = (const float*)d_in[6];
    const float* wb1 = (const float*)d_in[7];
    const float* bb1 = (const float*)d_in[8];
    const float* wb2 = (const float*)d_in[9];
    const float* bb2 = (const float*)d_in[10];
    const float* wc1 = (const float*)d_in[11];
    const float* bc1 = (const float*)d_in[12];
    const float* w3  = (const float*)d_in[13];
    const float* b3  = (const float*)d_in[14];
    float* out = (float*)d_out;
    float* ws  = (float*)d_ws;

    // Workspace (floats), peak 39,321,600 = 157.3 MB:
    //   h0 [8,32,320,320] @0 ; h1 [8,64,160,160] @26214400
    //   y  @0 ; b1f @13107200 ; bf @19660800 ; h2 @26214400 (reuse)
    float* h0  = ws;
    float* h1  = ws + 26214400L;
    float* yb  = ws;
    float* b1f = ws + 13107200L;
    float* bf  = ws + 19660800L;
    float* h2  = ws + 26214400L;

    const dim3 blk(256, 1, 1);
    const long HW1 = 25600;       // 160*160

    // conv0: 3->32, s2, 640->320. 20x20 tiles.
    conv3x3_lds<3, 32, 2, false><<<dim3(400, 1, 8), blk, 0, stream>>>(
        x, 3L * 640 * 640, w0, b0, h0, 32L * 320 * 320, nullptr, 0,
        640, 640, 320, 320);

    // conv1: 32->64, s2, 320->160. CO=64, input fetched once.
    conv3x3_lds<32, 64, 2, false><<<dim3(100, 1, 8), blk, 0, stream>>>(
        h0, 32L * 320 * 320, w1, b1, h1, 64L * HW1, nullptr, 0,
        320, 320, 160, 160);

    // wc0: 1x1 64->64 on h1 -> y. co chunks of 32.
    conv1x1_k<64, 0, 32><<<dim3(100, 2, 8), blk, 0, stream>>>(
        h1, 64L * HW1, h1, 64L * HW1, wc0, bc0, yb, 64L * HW1, (int)HW1);

    // wb1: 3x3 s1 32->32 on x2 (= y channels 32..63) -> b1f
    conv3x3_lds<32, 32, 1, false><<<dim3(100, 1, 8), blk, 0, stream>>>(
        yb + 32 * HW1, 64L * HW1, wb1, bb1, b1f, 32L * HW1, nullptr, 0,
        160, 160, 160, 160);

    // wb2: 3x3 s1 32->32 on b1f, + residual x2 -> bf
    conv3x3_lds<32, 32, 1, true><<<dim3(100, 1, 8), blk, 0, stream>>>(
        b1f, 32L * HW1, wb2, bb2, bf, 32L * HW1, yb + 32 * HW1, 64L * HW1,
        160, 160, 160, 160);

    // wc1: 1x1 on concat([y(64), bf(32)]) -> 64 -> h2. co chunks of 32.
    conv1x1_k<64, 32, 32><<<dim3(100, 2, 8), blk, 0, stream>>>(
        yb, 64L * HW1, bf, 32L * HW1, wc1, bc1, h2, 64L * HW1, (int)HW1);

    // conv3: 3x3 s2 64->128, 160->80 -> out. co chunks of 32 (4 chunks).
    conv3x3_lds<64, 32, 2, false><<<dim3(25, 4, 8), blk, 0, stream>>>(
        h2, 64L * HW1, w3, b3, out, 128L * 6400, nullptr, 0,
        160, 160, 80, 80);
}